// Round 1
// baseline (697.942 us; speedup 1.0000x reference)
//
#include <hip/hip_runtime.h>

typedef unsigned short u16;
typedef unsigned int u32;
typedef float f32x4 __attribute__((ext_vector_type(4)));
typedef __bf16 bf16x8 __attribute__((ext_vector_type(8)));

#define M_ALL 155648.0f
#define XP 264            // xs pitch (u16): 16B-aligned rows, 132 dw = 4 mod 32 -> 2-way max
#define YBP 152           // yb pitch (u16)
#define ATP 72            // at kv-pitch: 36 dw = 4 mod 32 -> 2-way max, 16B aligned
#define ZBP 153           // zbuf pitch

__device__ __forceinline__ u16 f2bf(float f) {
  union { float f; u32 u; } x; x.f = f;
  u32 u = x.u;
  u += 0x7FFFu + ((u >> 16) & 1u);   // RNE
  return (u16)(u >> 16);
}
__device__ __forceinline__ float bf2f(u16 h) {
  union { u32 u; float f; } x; x.u = ((u32)h) << 16;
  return x.f;
}
__device__ __forceinline__ f32x4 zero4() { f32x4 z = {0.f, 0.f, 0.f, 0.f}; return z; }

// ---------- prep: L2-normalize adjacency rows (bf16) + zero stat buffers ----------
__global__ void k_prep(const float* __restrict__ para, u16* __restrict__ wa,
                       float* __restrict__ stats) {
  int tid = threadIdx.x;
  for (int i = tid; i < 2048; i += 512) stats[i] = 0.f;   // 1536 y-stats + 512 z-stats
  if (tid < 456) {                                        // 3*8*19 rows
    int k = tid / 152, rem = tid % 152, g = rem / 19, v = rem % 19;
    int base = ((k * 8 + g) * 19 + v) * 19;
    float ss = 0.f;
    #pragma unroll
    for (int w = 0; w < 19; ++w) { float a = para[base + w]; ss += a * a; }
    float inv = 1.f / (sqrtf(ss) + 1e-4f);
    #pragma unroll
    for (int w = 0; w < 19; ++w) wa[base + w] = f2bf(para[base + w] * inv);
  }
}

// ---------- transpose linear_weight (256x768 f32) -> Wt[d][c] bf16 ----------
__global__ void k_wt(const float* __restrict__ W, u16* __restrict__ wt) {
  int idx = blockIdx.x * 512 + threadIdx.x;   // exactly 196608
  int d = idx >> 8, c = idx & 255;
  wt[idx] = f2bf(W[c * 768 + d]);
}

// ---------- pass S: GEMM y_raw = X*W, accumulate per-d sum & sumsq ----------
__global__ __launch_bounds__(512, 2) void k_stats(const float* __restrict__ x,
                                                  const u16* __restrict__ wt,
                                                  float* __restrict__ sumy) {
  __shared__ u16 xs[152 * XP];     // 80256 B
  __shared__ float scr[768];       // cross-wave stat reduce
  int tid = threadIdx.x;
  int bid = blockIdx.x;
  int n = bid >> 5, tg = bid & 31;
  const float* xbase = x + (size_t)(n * 256 + tg * 8) * 4864;

  {  // stage x slab (152 rows x 256 cols) as bf16
    int r = tid >> 6, c4 = (tid & 63) << 2;
    for (int it = 0; it < 19; ++it) {
      int m = it * 8 + r;
      float4 f = *reinterpret_cast<const float4*>(xbase + m * 256 + c4);
      uint2 p;
      p.x = (u32)f2bf(f.x) | ((u32)f2bf(f.y) << 16);
      p.y = (u32)f2bf(f.z) | ((u32)f2bf(f.w) << 16);
      *reinterpret_cast<uint2*>(&xs[m * XP + c4]) = p;
    }
  }
  __syncthreads();

  int lane = tid & 63, wave = tid >> 6;
  int mhalf = wave & 1, nt3 = wave >> 1;     // wave = M-half x N-triple
  int cl = lane & 15, q = lane >> 4;
  const bf16x8* wtv = reinterpret_cast<const bf16x8*>(wt);
  int arow[5];
  #pragma unroll
  for (int i = 0; i < 5; ++i) {
    int rr = mhalf * 80 + i * 16 + cl;
    arow[i] = (rr > 151 ? 151 : rr) * XP;    // clamp pad rows (masked in stats)
  }
  float msk4 = (mhalf == 1 && q >= 2) ? 0.f : 1.f;   // drop clamped rows 152..159

  for (int nc = 0; nc < 4; ++nc) {
    f32x4 acc[5][3];
    #pragma unroll
    for (int i = 0; i < 5; ++i)
      #pragma unroll
      for (int jj = 0; jj < 3; ++jj) acc[i][jj] = zero4();

    for (int s = 0; s < 8; ++s) {
      int kof = s * 32 + q * 8;
      bf16x8 b[3];
      #pragma unroll
      for (int jj = 0; jj < 3; ++jj) {
        int j = nt3 * 3 + jj;
        int d = (j >> 2) * 256 + nc * 64 + (j & 3) * 16 + cl;
        b[jj] = wtv[d * 32 + s * 4 + q];
      }
      #pragma unroll
      for (int i = 0; i < 5; ++i) {
        bf16x8 a = *reinterpret_cast<const bf16x8*>(&xs[arow[i] + kof]);
        #pragma unroll
        for (int jj = 0; jj < 3; ++jj)
          acc[i][jj] = __builtin_amdgcn_mfma_f32_16x16x32_bf16(a, b[jj], acc[i][jj], 0, 0, 0);
      }
    }
    #pragma unroll
    for (int jj = 0; jj < 3; ++jj) {
      float ps = 0.f, qs = 0.f;
      #pragma unroll
      for (int i = 0; i < 5; ++i) {
        float im = (i == 4) ? msk4 : 1.f;
        #pragma unroll
        for (int r = 0; r < 4; ++r) { float v = acc[i][jj][r] * im; ps += v; qs += v * v; }
      }
      ps += __shfl_xor(ps, 16); ps += __shfl_xor(ps, 32);
      qs += __shfl_xor(qs, 16); qs += __shfl_xor(qs, 32);
      if (lane < 16) { scr[wave * 96 + jj * 32 + lane] = ps; scr[wave * 96 + jj * 32 + 16 + lane] = qs; }
    }
    __syncthreads();
    if (tid < 384) {
      int nt = tid / 96, r = tid % 96, jj = r / 32, comp = (r & 31) >> 4, l = r & 15;
      int a0 = (2 * nt) * 96 + jj * 32 + comp * 16 + l;
      float val = scr[a0] + scr[a0 + 96];
      int j = nt * 3 + jj;
      int d = (j >> 2) * 256 + nc * 64 + (j & 3) * 16 + l;
      atomicAdd(&sumy[comp * 768 + d], val);
    }
    __syncthreads();
  }
}

// ---------- fold BN1 into per-d affine (bias cancels through training-mode BN) ----------
__global__ void k_f1(const float* __restrict__ stats, const float* __restrict__ gam,
                     const float* __restrict__ bet, float* __restrict__ ST) {
  int d = threadIdx.x;  // 768
  float inv = 1.f / M_ALL;
  float mr = stats[d] * inv;
  float qv = stats[768 + d] * inv;
  float var = qv - mr * mr;
  float Sc = gam[d] * rsqrtf(var + 1e-5f);
  ST[d] = Sc;
  ST[768 + d] = bet[d] - mr * Sc;
}

// ---------- main: GEMM + BN1 affine + adjacency MFMA + residual; write z; z-stats ----------
__global__ __launch_bounds__(512, 2) void k_main(const float* __restrict__ x,
                                                 const u16* __restrict__ wt,
                                                 const u16* __restrict__ wa,
                                                 const float* __restrict__ ST,
                                                 float* __restrict__ sumz,
                                                 float* __restrict__ out) {
  __shared__ u16 xs[152 * XP];        // 80256 B
  __shared__ u16 yb[3 * 64 * YBP];    // 58368 B  (also reused as zbuf + scratch)
  __shared__ u16 at[8 * 20 * ATP];    // 23040 B  At[g][w][kv], w=19 row zeroed
  int tid = threadIdx.x;
  int bid = blockIdx.x;
  int n = bid >> 5, tg = bid & 31;
  const float* xbase = x + (size_t)(n * 256 + tg * 8) * 4864;
  size_t obase = (size_t)(n * 256 + tg * 8) * 4864;

  // build At (transposed, kv-padded, zero rows for kv>=57 and w>=19)
  for (int i = tid; i < 8 * 20 * ATP; i += 512) {
    int g = i / (20 * ATP), r = i % (20 * ATP), w = r / ATP, kv = r % ATP;
    u16 val = 0;
    if (w < 19 && kv < 57) {
      int k = kv / 19, v = kv - 19 * k;
      val = wa[((k * 8 + g) * 19 + v) * 19 + w];
    }
    at[i] = val;
  }
  {  // stage x slab
    int r = tid >> 6, c4 = (tid & 63) << 2;
    for (int it = 0; it < 19; ++it) {
      int m = it * 8 + r;
      float4 f = *reinterpret_cast<const float4*>(xbase + m * 256 + c4);
      uint2 p;
      p.x = (u32)f2bf(f.x) | ((u32)f2bf(f.y) << 16);
      p.y = (u32)f2bf(f.z) | ((u32)f2bf(f.w) << 16);
      *reinterpret_cast<uint2*>(&xs[m * XP + c4]) = p;
    }
  }
  __syncthreads();

  int lane = tid & 63, wave = tid >> 6;
  int mhalf = wave & 1, nt3 = wave >> 1;
  int cl = lane & 15, q = lane >> 4;
  int g = wave;                                  // adjacency: wave owns group g
  const bf16x8* wtv = reinterpret_cast<const bf16x8*>(wt);
  float* scrz = reinterpret_cast<float*>(&yb[9792]);   // 1024 floats (after zbuf)
  u16* zbuf = yb;                                      // [64][ZBP]
  int arow[5];
  #pragma unroll
  for (int i = 0; i < 5; ++i) {
    int rr = mhalf * 80 + i * 16 + cl;
    arow[i] = (rr > 151 ? 151 : rr) * XP;
  }
  int aoff[2][8];    // yb offsets per (ks, elem): k*64*YBP + v, clamped
  #pragma unroll
  for (int ks = 0; ks < 2; ++ks)
    #pragma unroll
    for (int e = 0; e < 8; ++e) {
      int kv = ks * 32 + q * 8 + e;
      if (kv > 56) kv = 0;
      int k = kv / 19, v = kv - 19 * k;
      aoff[ks][e] = k * (64 * YBP) + v;
    }

  for (int nc = 0; nc < 4; ++nc) {
    // ---- GEMM (regs only) ----
    f32x4 acc[5][3];
    #pragma unroll
    for (int i = 0; i < 5; ++i)
      #pragma unroll
      for (int jj = 0; jj < 3; ++jj) acc[i][jj] = zero4();
    for (int s = 0; s < 8; ++s) {
      int kof = s * 32 + q * 8;
      bf16x8 b[3];
      #pragma unroll
      for (int jj = 0; jj < 3; ++jj) {
        int j = nt3 * 3 + jj;
        int d = (j >> 2) * 256 + nc * 64 + (j & 3) * 16 + cl;
        b[jj] = wtv[d * 32 + s * 4 + q];
      }
      #pragma unroll
      for (int i = 0; i < 5; ++i) {
        bf16x8 a = *reinterpret_cast<const bf16x8*>(&xs[arow[i] + kof]);
        #pragma unroll
        for (int jj = 0; jj < 3; ++jj)
          acc[i][jj] = __builtin_amdgcn_mfma_f32_16x16x32_bf16(a, b[jj], acc[i][jj], 0, 0, 0);
      }
    }
    __syncthreads();   // B0: previous chunk's zbuf/scratch consumers are done

    // ---- BN1 affine, pack bf16, write yb[k][c_local][m] ----
    #pragma unroll
    for (int jj = 0; jj < 3; ++jj) {
      int j = nt3 * 3 + jj;
      int ksub = j >> 2;
      int d = ksub * 256 + nc * 64 + (j & 3) * 16 + cl;
      float Sc = ST[d], Tc = ST[768 + d];
      int clloc = (j & 3) * 16 + cl;
      #pragma unroll
      for (int i = 0; i < 5; ++i) {
        int m = mhalf * 80 + i * 16 + q * 4;
        if (m < 152) {
          uint2 p;
          float v0 = acc[i][jj][0] * Sc + Tc;
          float v1 = acc[i][jj][1] * Sc + Tc;
          float v2 = acc[i][jj][2] * Sc + Tc;
          float v3 = acc[i][jj][3] * Sc + Tc;
          p.x = (u32)f2bf(v0) | ((u32)f2bf(v1) << 16);
          p.y = (u32)f2bf(v2) | ((u32)f2bf(v3) << 16);
          *reinterpret_cast<uint2*>(&yb[(ksub * 64 + clloc) * YBP + m]) = p;
        }
      }
    }
    __syncthreads();   // B1: yb complete

    // ---- adjacency MFMA: out[(t,c8), w] = sum_kv Y[(t,c8),kv] * At[g][w][kv] ----
    f32x4 zacc[4][2];
    #pragma unroll
    for (int mt = 0; mt < 4; ++mt) { zacc[mt][0] = zero4(); zacc[mt][1] = zero4(); }
    #pragma unroll
    for (int ks = 0; ks < 2; ++ks) {
      bf16x8 bfr[2];
      #pragma unroll
      for (int nt = 0; nt < 2; ++nt) {
        int w = nt * 16 + cl; if (w > 19) w = 19;   // zeroed clamp row
        bfr[nt] = *reinterpret_cast<const bf16x8*>(&at[(g * 20 + w) * ATP + ks * 32 + q * 8]);
      }
      #pragma unroll
      for (int mt = 0; mt < 4; ++mt) {
        int tc = mt * 16 + cl;
        int t = tc >> 3, c8 = tc & 7;
        int ybase = (c8 * 8 + g) * YBP + t * 19;
        union { bf16x8 v; u16 u[8]; } afr;
        #pragma unroll
        for (int e = 0; e < 8; ++e) afr.u[e] = yb[aoff[ks][e] + ybase];
        #pragma unroll
        for (int nt = 0; nt < 2; ++nt)
          zacc[mt][nt] = __builtin_amdgcn_mfma_f32_16x16x32_bf16(afr.v, bfr[nt], zacc[mt][nt], 0, 0, 0);
      }
    }
    __syncthreads();   // B2: all yb reads done

    // ---- spill out1 to zbuf (bf16) ----
    #pragma unroll
    for (int mt = 0; mt < 4; ++mt)
      #pragma unroll
      for (int nt = 0; nt < 2; ++nt)
        #pragma unroll
        for (int r = 0; r < 4; ++r) {
          int w = nt * 16 + cl;
          if (w < 19) {
            int tc = mt * 16 + q * 4 + r;
            int t = tc >> 3, c8 = tc & 7;
            zbuf[(c8 * 8 + g) * ZBP + t * 19 + w] = f2bf(zacc[mt][nt][r]);
          }
        }
    __syncthreads();   // B3: zbuf complete

    // ---- z = out1 + x (residual), coalesced store, z-stats ----
    float sz = 0.f, sq = 0.f;
    int cloc = tid & 63;
    int cglob = nc * 64 + cloc;
    #pragma unroll 1
    for (int rep = 0; rep < 19; ++rep) {
      int idx = rep * 512 + tid;
      int mp = idx >> 6;
      float z = bf2f(zbuf[cloc * ZBP + mp]) + bf2f(xs[mp * XP + cglob]);
      out[obase + (size_t)mp * 256 + cglob] = z;
      sz += z; sq += z * z;
    }
    scrz[cloc * 8 + (tid >> 6)] = sz;
    scrz[512 + cloc * 8 + (tid >> 6)] = sq;
    __syncthreads();   // B4: scratch complete
    if (tid < 128) {
      int comp = tid >> 6, c = tid & 63;
      float v = 0.f;
      #pragma unroll
      for (int h = 0; h < 8; ++h) v += scrz[comp * 512 + c * 8 + h];
      atomicAdd(&sumz[comp * 256 + nc * 64 + c], v);
    }
    // next GEMM touches no shared writes; B0 protects scratch readers
  }
}

// ---------- fold BN2 ----------
__global__ void k_f2(const float* __restrict__ statz, const float* __restrict__ gam,
                     const float* __restrict__ bet, float* __restrict__ S1T1) {
  int c = threadIdx.x;  // 256
  float inv = 1.f / M_ALL;
  float mz = statz[c] * inv;
  float qv = statz[256 + c] * inv;
  float var = qv - mz * mz;
  float Sc = gam[c] * rsqrtf(var + 1e-5f);
  S1T1[c] = Sc;
  S1T1[256 + c] = bet[c] - mz * Sc;
}

// ---------- BN2 affine + ReLU, in-place on d_out ----------
__global__ __launch_bounds__(256) void k_relu(float* __restrict__ out,
                                              const float* __restrict__ S1T1) {
  int tid = threadIdx.x;
  int lane = tid & 63;
  int wv = ((blockIdx.x << 8) + tid) >> 6;     // 0..8191 global wave id
  const float4* s14 = reinterpret_cast<const float4*>(S1T1);
  float4 sv = s14[lane], tv = s14[64 + lane];
  float4* o4 = reinterpret_cast<float4*>(out);
  #pragma unroll 1
  for (int r = 0; r < 19; ++r) {               // 155648 rows / 8192 waves
    size_t i = ((size_t)r * 8192 + wv) * 64 + lane;
    float4 f = o4[i];
    f.x = fmaxf(f.x * sv.x + tv.x, 0.f);
    f.y = fmaxf(f.y * sv.y + tv.y, 0.f);
    f.z = fmaxf(f.z * sv.z + tv.z, 0.f);
    f.w = fmaxf(f.w * sv.w + tv.w, 0.f);
    o4[i] = f;
  }
}

extern "C" void kernel_launch(void* const* d_in, const int* in_sizes, int n_in,
                              void* d_out, int out_size, void* d_ws, size_t ws_size,
                              hipStream_t stream) {
  const float* x    = (const float*)d_in[0];
  const float* para = (const float*)d_in[1];
  const float* W    = (const float*)d_in[2];
  // d_in[3] linear_bias: cancels through training-mode BN — unused
  const float* bng  = (const float*)d_in[4];
  const float* bnb  = (const float*)d_in[5];
  const float* bn1g = (const float*)d_in[6];
  const float* bn1b = (const float*)d_in[7];
  float* out = (float*)d_out;

  char* ws = (char*)d_ws;
  u16* wt    = (u16*)ws;                      // 196608 u16 = 393216 B
  u16* wa    = (u16*)(ws + 393216);           // 8664 u16
  float* st  = (float*)(ws + 410560);         // 1536 y-stats + 512 z-stats
  float* sumy = st;
  float* sumz = st + 1536;
  float* ST   = (float*)(ws + 418752);        // 768 S + 768 T
  float* S1T1 = (float*)(ws + 424896);        // 256 S1 + 256 T1

  k_prep<<<dim3(1),    dim3(512), 0, stream>>>(para, wa, st);
  k_wt  <<<dim3(384),  dim3(512), 0, stream>>>(W, wt);
  k_stats<<<dim3(1024), dim3(512), 0, stream>>>(x, wt, sumy);
  k_f1  <<<dim3(1),    dim3(768), 0, stream>>>(sumy, bng, bnb, ST);
  k_main<<<dim3(1024), dim3(512), 0, stream>>>(x, wt, wa, ST, sumz, out);
  k_f2  <<<dim3(1),    dim3(256), 0, stream>>>(sumz, bn1g, bn1b, S1T1);
  k_relu<<<dim3(2048), dim3(256), 0, stream>>>(out, S1T1);
}

// Round 2
// 628.795 us; speedup vs baseline: 1.1100x; 1.1100x over previous
//
#include <hip/hip_runtime.h>

typedef unsigned short u16;
typedef unsigned int u32;
typedef float f32x4 __attribute__((ext_vector_type(4)));
typedef __bf16 bf16x8 __attribute__((ext_vector_type(8)));

#define M_ALL 155648.0f
#define GP 168            // k_gram xsT pitch (u16): 84 dw stride -> 8-quad spread, 16B aligned

__device__ __forceinline__ u16 f2bf(float f) {
  union { float f; u32 u; } x; x.f = f;
  u32 u = x.u;
  u += 0x7FFFu + ((u >> 16) & 1u);   // RNE
  return (u16)(u >> 16);
}
__device__ __forceinline__ float bf2f(u16 h) {
  union { u32 u; float f; } x; x.u = ((u32)h) << 16;
  return x.f;
}
__device__ __forceinline__ f32x4 zero4() { f32x4 z = {0.f, 0.f, 0.f, 0.f}; return z; }

// xs swizzled index: row m (0..151), col c (0..255), 16B chunks XORed with m&7
__device__ __forceinline__ int xs_idx(int m, int c) {
  return m * 256 + ((((c >> 3) ^ (m & 7)) << 3) | (c & 7));
}
// Y2 swizzled index: row r (0..511), col kvp (0..63), chunk ^= (r&7)^((r>>3)&7)
__device__ __forceinline__ int y2_idx(int r, int kvp) {
  int sw = (r & 7) ^ ((r >> 3) & 7);
  return r * 64 + ((((kvp >> 3) ^ sw) << 3) | (kvp & 7));
}

// ---------- prep: L2-normalize adjacency rows, build wa2[g][w(20)][kvp(64)] bf16 ----------
__global__ void k_prep(const float* __restrict__ para, u16* __restrict__ wa2) {
  __shared__ float aL[3 * 8 * 19 * 19];
  int tid = threadIdx.x;
  if (tid < 456) {                                        // 3*8*19 rows
    int k = tid / 152, rem = tid % 152, g = rem / 19, v = rem % 19;
    int base = ((k * 8 + g) * 19 + v) * 19;
    float ss = 0.f;
    #pragma unroll
    for (int w = 0; w < 19; ++w) { float a = para[base + w]; ss += a * a; }
    float inv = 1.f / (sqrtf(ss) + 1e-4f);
    #pragma unroll
    for (int w = 0; w < 19; ++w) aL[base + w] = para[base + w] * inv;
  }
  __syncthreads();
  for (int i = tid; i < 8 * 20 * 64; i += 512) {
    int g = i / 1280, rem = i % 1280, w = rem >> 6, kvp = rem & 63;
    u16 val = 0;
    if (w < 19 && kvp < 57) {
      int k = kvp / 19, v = kvp - 19 * k;
      val = f2bf(aL[((k * 8 + g) * 19 + v) * 19 + w]);
    }
    wa2[i] = val;
  }
}

// ---------- transpose linear_weight (256x768 f32) -> Wt[d][c] bf16 ----------
__global__ void k_wt(const float* __restrict__ W, u16* __restrict__ wt) {
  int idx = blockIdx.x * 512 + threadIdx.x;   // exactly 196608
  int d = idx >> 8, c = idx & 255;
  wt[idx] = f2bf(W[c * 768 + d]);
}

// ---------- Gram pass: G = X^T X (bf16 MFMA, fp32 acc), + colsum(x) ----------
__global__ __launch_bounds__(512, 2) void k_gram(const float* __restrict__ x,
                                                 float* __restrict__ G,
                                                 float* __restrict__ colsum) {
  __shared__ u16 xsT[256 * GP];    // 86016 B, [c][m] bf16, m padded 152..159 = 0
  __shared__ float scs[512];
  int tid = threadIdx.x, bid = blockIdx.x;
  int c = tid & 255, mh = tid >> 8;
  int lane = tid & 63, wave = tid >> 6;
  int cl = lane & 15, q = lane >> 4;

  if (tid < 256) {   // zero pad columns m=152..159 once
    *reinterpret_cast<uint2*>(&xsT[tid * GP + 152]) = make_uint2(0u, 0u);
    *reinterpret_cast<uint2*>(&xsT[tid * GP + 156]) = make_uint2(0u, 0u);
  }

  float cs = 0.f;
  f32x4 acc[2][16];
  #pragma unroll
  for (int ri = 0; ri < 2; ++ri)
    #pragma unroll
    for (int j = 0; j < 16; ++j) acc[ri][j] = zero4();

  for (int ss = 0; ss < 4; ++ss) {
    int sl = bid * 4 + ss;
    const float* xb = x + (size_t)sl * 152 * 256;
    __syncthreads();   // prev-slab reads done before overwrite (also orders pad-zero)
    #pragma unroll 1
    for (int it = 0; it < 19; ++it) {
      int m0 = it * 8 + mh * 4;
      float v0 = xb[(m0 + 0) * 256 + c];
      float v1 = xb[(m0 + 1) * 256 + c];
      float v2 = xb[(m0 + 2) * 256 + c];
      float v3 = xb[(m0 + 3) * 256 + c];
      cs += v0 + v1 + v2 + v3;
      uint2 p;
      p.x = (u32)f2bf(v0) | ((u32)f2bf(v1) << 16);
      p.y = (u32)f2bf(v2) | ((u32)f2bf(v3) << 16);
      *reinterpret_cast<uint2*>(&xsT[c * GP + m0]) = p;
    }
    __syncthreads();
    // Gram MFMA: wave owns G tile-rows {wave, wave+8}, all 16 tile-cols
    #pragma unroll
    for (int s = 0; s < 5; ++s) {
      int kof = s * 32 + q * 8;
      bf16x8 a0 = *reinterpret_cast<const bf16x8*>(&xsT[(wave * 16 + cl) * GP + kof]);
      bf16x8 a1 = *reinterpret_cast<const bf16x8*>(&xsT[((wave + 8) * 16 + cl) * GP + kof]);
      #pragma unroll
      for (int ct2 = 0; ct2 < 16; ++ct2) {
        bf16x8 b = *reinterpret_cast<const bf16x8*>(&xsT[(ct2 * 16 + cl) * GP + kof]);
        acc[0][ct2] = __builtin_amdgcn_mfma_f32_16x16x32_bf16(a0, b, acc[0][ct2], 0, 0, 0);
        acc[1][ct2] = __builtin_amdgcn_mfma_f32_16x16x32_bf16(a1, b, acc[1][ct2], 0, 0, 0);
      }
    }
  }
  // emit upper triangle only (k_sym fills the rest)
  #pragma unroll
  for (int ri = 0; ri < 2; ++ri) {
    int ct = wave + ri * 8;
    #pragma unroll
    for (int ct2 = 0; ct2 < 16; ++ct2) {
      if (ct2 >= ct) {
        #pragma unroll
        for (int r4 = 0; r4 < 4; ++r4)
          atomicAdd(&G[(ct * 16 + q * 4 + r4) * 256 + ct2 * 16 + cl], acc[ri][ct2][r4]);
      }
    }
  }
  scs[tid] = cs;
  __syncthreads();
  if (tid < 256) atomicAdd(&colsum[tid], scs[tid] + scs[tid + 256]);
}

// ---------- symmetrize G ----------
__global__ void k_sym(float* __restrict__ G) {
  int i = blockIdx.x * 256 + threadIdx.x;   // 65536
  int r = i >> 8, cN = i & 255;
  if (r > cN) G[i] = G[cN * 256 + r];
}

// ---------- fold BN1: S,T per d from Gram quad-form ----------
__global__ __launch_bounds__(256) void k_f1(const float* __restrict__ G,
                                            const float* __restrict__ colsum,
                                            const float* __restrict__ W,
                                            const float* __restrict__ gam,
                                            const float* __restrict__ bet,
                                            float* __restrict__ ST) {
  __shared__ float wd[256];
  __shared__ float red[16];
  int d = blockIdx.x, c = threadIdx.x;
  float wv = W[c * 768 + d];
  wd[c] = wv;
  __syncthreads();
  float dot = 0.f;
  const float* Gr = G + c * 256;
  #pragma unroll 4
  for (int j = 0; j < 256; ++j) dot += Gr[j] * wd[j];
  float part = wv * dot;
  float mpart = colsum[c] * wv;
  #pragma unroll
  for (int o = 32; o; o >>= 1) { part += __shfl_down(part, o); mpart += __shfl_down(mpart, o); }
  int lane = c & 63, w = c >> 6;
  if (lane == 0) { red[w] = part; red[8 + w] = mpart; }
  __syncthreads();
  if (c == 0) {
    float qv = red[0] + red[1] + red[2] + red[3];
    float ms = red[8] + red[9] + red[10] + red[11];
    float mean = ms / M_ALL;
    float var = qv / M_ALL - mean * mean;
    float S = gam[d] * rsqrtf(var + 1e-5f);
    ST[d] = S;
    ST[768 + d] = bet[d] - mean * S;
  }
}

// ---------- main: GEMM + BN1 affine + adjacency MFMA + residual; write z; z-stats ----------
__global__ __launch_bounds__(512, 2) void k_main(const float* __restrict__ x,
                                                 const u16* __restrict__ wt,
                                                 const u16* __restrict__ wa2,
                                                 const float* __restrict__ ST,
                                                 float* __restrict__ sumz,
                                                 float* __restrict__ out) {
  __shared__ u16 xs[152 * 256];       // 77824 B, swizzled
  __shared__ u16 y2[512 * 64];        // 65536 B, [r=(t,c_local)][kvp] swizzled; reused as f32 zbuf
  __shared__ float scrz[1024];        // 4096 B stat scratch
  int tid = threadIdx.x;
  int bid = blockIdx.x;
  const float* xbase = x + (size_t)bid * 152 * 256;
  size_t obase = (size_t)bid * 152 * 256;

  {  // stage x slab (swizzled bf16)
    int r = tid >> 6, c4 = (tid & 63) << 2;
    for (int it = 0; it < 19; ++it) {
      int m = it * 8 + r;
      float4 f = *reinterpret_cast<const float4*>(xbase + m * 256 + c4);
      uint2 p;
      p.x = (u32)f2bf(f.x) | ((u32)f2bf(f.y) << 16);
      p.y = (u32)f2bf(f.z) | ((u32)f2bf(f.w) << 16);
      *reinterpret_cast<uint2*>(&xs[xs_idx(m, c4)]) = p;
    }
  }

  int lane = tid & 63, wave = tid >> 6;
  int mhalf = wave & 1, nt3 = wave >> 1;
  int cl = lane & 15, q = lane >> 4;
  int g = wave;                                  // adjacency: wave owns group g
  const bf16x8* wtv = reinterpret_cast<const bf16x8*>(wt);
  float* zbufF = reinterpret_cast<float*>(y2);   // [64 c][153 m] f32

  // adjacency B-frags: registers, loaded once from global (L2-hot)
  bf16x8 bfr[2][2];
  #pragma unroll
  for (int ks = 0; ks < 2; ++ks)
    #pragma unroll
    for (int nt = 0; nt < 2; ++nt) {
      int w = nt * 16 + cl; int wc = (w < 20) ? w : 19;
      bfr[ks][nt] = *reinterpret_cast<const bf16x8*>(&wa2[(g * 20 + wc) * 64 + ks * 32 + q * 8]);
    }

  int arow[5], mlow[5];
  #pragma unroll
  for (int i = 0; i < 5; ++i) {
    int rr = mhalf * 80 + i * 16 + cl;
    if (rr > 151) rr = 151;
    arow[i] = rr * 256; mlow[i] = rr & 7;
  }
  __syncthreads();

  for (int nc = 0; nc < 4; ++nc) {
    // ---- GEMM (regs only) ----
    f32x4 acc[5][3];
    #pragma unroll
    for (int i = 0; i < 5; ++i)
      #pragma unroll
      for (int jj = 0; jj < 3; ++jj) acc[i][jj] = zero4();
    for (int s = 0; s < 8; ++s) {
      int sq4 = s * 4 + q;
      bf16x8 b[3];
      #pragma unroll
      for (int jj = 0; jj < 3; ++jj) {
        int j = nt3 * 3 + jj;
        int d = (j >> 2) * 256 + nc * 64 + (j & 3) * 16 + cl;
        b[jj] = wtv[d * 32 + sq4];
      }
      #pragma unroll
      for (int i = 0; i < 5; ++i) {
        bf16x8 a = *reinterpret_cast<const bf16x8*>(&xs[arow[i] + ((sq4 ^ mlow[i]) << 3)]);
        #pragma unroll
        for (int jj = 0; jj < 3; ++jj)
          acc[i][jj] = __builtin_amdgcn_mfma_f32_16x16x32_bf16(a, b[jj], acc[i][jj], 0, 0, 0);
      }
    }
    __syncthreads();   // B0: prev-nc zbuf/scrz consumers done; y2 free

    // ---- re-zero kvp 57..63 (zbuf overlay clobbered them) ----
    #pragma unroll
    for (int kk = 0; kk < 7; ++kk)
      y2[y2_idx(tid, 57 + kk)] = 0;

    // ---- BN1 affine, pack bf16, write y2[(t,c_local)][kvp] ----
    #pragma unroll
    for (int jj = 0; jj < 3; ++jj) {
      int j = nt3 * 3 + jj;
      int ksub = j >> 2;
      int c_local = (j & 3) * 16 + cl;
      int d = ksub * 256 + nc * 64 + c_local;
      float Sc = ST[d], Tc = ST[768 + d];
      #pragma unroll
      for (int i = 0; i < 5; ++i) {
        int mb = mhalf * 80 + i * 16 + q * 4;
        #pragma unroll
        for (int r4 = 0; r4 < 4; ++r4) {
          int m = mb + r4;
          if (m < 152) {
            int t = (m * 27) >> 9;
            int v = m - t * 19;
            int kvp = ksub * 19 + v;
            int r = t * 64 + c_local;
            y2[y2_idx(r, kvp)] = f2bf(acc[i][jj][r4] * Sc + Tc);
          }
        }
      }
    }
    __syncthreads();   // B1: y2 complete

    // ---- adjacency MFMA: out1[(t,c8),w] = sum_kvp Y[(t,c8+8g... )][kvp] * A ----
    f32x4 zacc[4][2];
    #pragma unroll
    for (int mt = 0; mt < 4; ++mt) { zacc[mt][0] = zero4(); zacc[mt][1] = zero4(); }
    #pragma unroll
    for (int ks = 0; ks < 2; ++ks) {
      #pragma unroll
      for (int mt = 0; mt < 4; ++mt) {
        int tc = mt * 16 + cl;
        int t = tc >> 3, c8 = tc & 7;
        int r = t * 64 + c8 * 8 + g;
        int ch = (ks * 4 + q) ^ g ^ c8;
        bf16x8 afr = *reinterpret_cast<const bf16x8*>(&y2[r * 64 + (ch << 3)]);
        #pragma unroll
        for (int nt = 0; nt < 2; ++nt)
          zacc[mt][nt] = __builtin_amdgcn_mfma_f32_16x16x32_bf16(afr, bfr[ks][nt], zacc[mt][nt], 0, 0, 0);
      }
    }
    __syncthreads();   // B2: all y2 reads done

    // ---- spill out1 (f32) to zbuf ----
    #pragma unroll
    for (int mt = 0; mt < 4; ++mt)
      #pragma unroll
      for (int nt = 0; nt < 2; ++nt) {
        int w = nt * 16 + cl;
        if (w < 19) {
          #pragma unroll
          for (int r4 = 0; r4 < 4; ++r4) {
            int mm = mt * 16 + q * 4 + r4;
            int t = mm >> 3, c8 = mm & 7;
            zbufF[(c8 * 8 + g) * 153 + t * 19 + w] = zacc[mt][nt][r4];
          }
        }
      }
    __syncthreads();   // B3: zbuf complete

    // ---- z = out1 + x (residual), coalesced store, z-stats ----
    float sz = 0.f, sq = 0.f;
    int cloc = tid & 63;
    int cglob = nc * 64 + cloc;
    #pragma unroll 1
    for (int rep = 0; rep < 19; ++rep) {
      int mp = rep * 8 + (tid >> 6);
      float z = zbufF[cloc * 153 + mp] + bf2f(xs[xs_idx(mp, cglob)]);
      out[obase + (size_t)mp * 256 + cglob] = z;
      sz += z; sq += z * z;
    }
    scrz[(tid >> 6) * 64 + cloc] = sz;
    scrz[512 + (tid >> 6) * 64 + cloc] = sq;
    __syncthreads();   // B4: scratch complete
    if (tid < 128) {
      int comp = tid >> 6, c = tid & 63;
      float v = 0.f;
      #pragma unroll
      for (int h = 0; h < 8; ++h) v += scrz[comp * 512 + h * 64 + c];
      atomicAdd(&sumz[comp * 256 + nc * 64 + c], v);
    }
  }
}

// ---------- fold BN2 ----------
__global__ void k_f2(const float* __restrict__ statz, const float* __restrict__ gam,
                     const float* __restrict__ bet, float* __restrict__ S1T1) {
  int c = threadIdx.x;  // 256
  float inv = 1.f / M_ALL;
  float mz = statz[c] * inv;
  float qv = statz[256 + c] * inv;
  float var = qv - mz * mz;
  float Sc = gam[c] * rsqrtf(var + 1e-5f);
  S1T1[c] = Sc;
  S1T1[256 + c] = bet[c] - mz * Sc;
}

// ---------- BN2 affine + ReLU, in-place on d_out ----------
__global__ __launch_bounds__(256) void k_relu(float* __restrict__ out,
                                              const float* __restrict__ S1T1) {
  int tid = threadIdx.x;
  int lane = tid & 63;
  int wv = ((blockIdx.x << 8) + tid) >> 6;     // 0..8191 global wave id
  const float4* s14 = reinterpret_cast<const float4*>(S1T1);
  float4 sv = s14[lane], tv = s14[64 + lane];
  float4* o4 = reinterpret_cast<float4*>(out);
  #pragma unroll 1
  for (int r = 0; r < 19; ++r) {               // 155648 rows / 8192 waves
    size_t i = ((size_t)r * 8192 + wv) * 64 + lane;
    float4 f = o4[i];
    f.x = fmaxf(f.x * sv.x + tv.x, 0.f);
    f.y = fmaxf(f.y * sv.y + tv.y, 0.f);
    f.z = fmaxf(f.z * sv.z + tv.z, 0.f);
    f.w = fmaxf(f.w * sv.w + tv.w, 0.f);
    o4[i] = f;
  }
}

extern "C" void kernel_launch(void* const* d_in, const int* in_sizes, int n_in,
                              void* d_out, int out_size, void* d_ws, size_t ws_size,
                              hipStream_t stream) {
  const float* x    = (const float*)d_in[0];
  const float* para = (const float*)d_in[1];
  const float* W    = (const float*)d_in[2];
  // d_in[3] linear_bias: cancels through training-mode BN — unused
  const float* bng  = (const float*)d_in[4];
  const float* bnb  = (const float*)d_in[5];
  const float* bn1g = (const float*)d_in[6];
  const float* bn1b = (const float*)d_in[7];
  float* out = (float*)d_out;

  char* ws = (char*)d_ws;
  u16* wt     = (u16*)ws;                     // 393216 B
  u16* wa2    = (u16*)(ws + 393216);          // 20480 B
  float* G    = (float*)(ws + 413696);        // 262144 B
  float* csum = (float*)(ws + 675840);        // 1024 B
  float* sumz = (float*)(ws + 676864);        // 2048 B
  float* ST   = (float*)(ws + 678912);        // 6144 B
  float* S1T1 = (float*)(ws + 685056);        // 2048 B

  hipMemsetAsync(ws + 413696, 0, 262144 + 1024 + 2048, stream);   // G, colsum, sumz
  k_prep<<<dim3(1),    dim3(512), 0, stream>>>(para, wa2);
  k_wt  <<<dim3(384),  dim3(512), 0, stream>>>(W, wt);
  k_gram<<<dim3(256),  dim3(512), 0, stream>>>(x, G, csum);
  k_sym <<<dim3(256),  dim3(256), 0, stream>>>(G);
  k_f1  <<<dim3(768),  dim3(256), 0, stream>>>(G, csum, W, bng, bnb, ST);
  k_main<<<dim3(1024), dim3(512), 0, stream>>>(x, wt, wa2, ST, sumz, out);
  k_f2  <<<dim3(1),    dim3(256), 0, stream>>>(sumz, bn1g, bn1b, S1T1);
  k_relu<<<dim3(2048), dim3(256), 0, stream>>>(out, S1T1);
}